// Round 1
// baseline (844.569 us; speedup 1.0000x reference)
//
#include <hip/hip_runtime.h>
#include <hip/hip_bf16.h>

#define N_NODES 100000
#define N_EDGES 600000
#define N_REL   3
#define D_INF   256
#define D_OUTF  128

// ---------------------------------------------------------------------------
// K1: projection GEMM  l = relu(x@Wl+bl), r = relu(x@Wr+br)
// block 256 threads = 64 col-threads (4 cols each, 256 combined cols) x 4 node groups (8 nodes)
// tile: 32 nodes x 256 cols, x tile staged in LDS (broadcast reads)
// ---------------------------------------------------------------------------
__global__ __launch_bounds__(256) void proj_kernel(
    const float* __restrict__ x,
    const float* __restrict__ Wl, const float* __restrict__ bl,
    const float* __restrict__ Wr, const float* __restrict__ br,
    float* __restrict__ lbuf, float* __restrict__ rbuf)
{
    __shared__ float xs[32 * 256];
    const int tid = threadIdx.x;
    const int nb  = blockIdx.x * 32;

    const float4* xg  = reinterpret_cast<const float4*>(x + (size_t)nb * D_INF);
    float4*       xls = reinterpret_cast<float4*>(xs);
#pragma unroll
    for (int j = 0; j < 8; ++j) xls[tid + j * 256] = xg[tid + j * 256];
    __syncthreads();

    const int cg = tid & 63;   // col group: 4 cols each
    const int ng = tid >> 6;   // node group: 8 nodes each

    const float* wbase;
    const float* bbase;
    float*       obase;
    if (cg < 32) { wbase = Wl + 4 * cg;        bbase = bl + 4 * cg;        obase = lbuf + 4 * cg; }
    else         { wbase = Wr + 4 * (cg - 32); bbase = br + 4 * (cg - 32); obase = rbuf + 4 * (cg - 32); }

    float acc[8][4];
#pragma unroll
    for (int i = 0; i < 8; ++i)
#pragma unroll
        for (int j = 0; j < 4; ++j) acc[i][j] = 0.f;

    const float* xrow = xs + ng * 8 * 256;
#pragma unroll 4
    for (int k = 0; k < 256; ++k) {
        const float4 w = *reinterpret_cast<const float4*>(wbase + k * D_OUTF);
#pragma unroll
        for (int i = 0; i < 8; ++i) {
            const float xv = xrow[i * 256 + k];
            acc[i][0] = fmaf(xv, w.x, acc[i][0]);
            acc[i][1] = fmaf(xv, w.y, acc[i][1]);
            acc[i][2] = fmaf(xv, w.z, acc[i][2]);
            acc[i][3] = fmaf(xv, w.w, acc[i][3]);
        }
    }

    const float4 bias = *reinterpret_cast<const float4*>(bbase);
#pragma unroll
    for (int i = 0; i < 8; ++i) {
        const int node = nb + ng * 8 + i;
        float4 o;
        o.x = fmaxf(acc[i][0] + bias.x, 0.f);
        o.y = fmaxf(acc[i][1] + bias.y, 0.f);
        o.z = fmaxf(acc[i][2] + bias.z, 0.f);
        o.w = fmaxf(acc[i][3] + bias.w, 0.f);
        *reinterpret_cast<float4*>(obase + (size_t)node * D_OUTF) = o;
    }
}

// ---------------------------------------------------------------------------
// K2: per-node attention scalars  al[n,r,h] = dot(l[n,h,:], attn[r,h,:C]),
//                                 ar[n,r,h] = dot(r[n,h,:], attn[r,h,C:])
// block 256 = 2 nodes x 128 channels; reduce over c via 32-lane shfl_xor
// ---------------------------------------------------------------------------
__global__ __launch_bounds__(256) void alar_kernel(
    const float* __restrict__ lbuf, const float* __restrict__ rbuf,
    const float* __restrict__ attn, float* __restrict__ al, float* __restrict__ ar)
{
    const int t    = threadIdx.x;
    const int node = blockIdx.x * 2 + (t >> 7);
    const int hc   = t & 127;
    const int h    = hc >> 5;
    const int c    = hc & 31;
    const float lv = lbuf[(size_t)node * D_OUTF + hc];
    const float rv = rbuf[(size_t)node * D_OUTF + hc];
#pragma unroll
    for (int rr = 0; rr < 3; ++rr) {
        float pa = lv * attn[rr * 256 + h * 64 + c];
        float pb = rv * attn[rr * 256 + h * 64 + 32 + c];
#pragma unroll
        for (int m = 16; m >= 1; m >>= 1) {
            pa += __shfl_xor(pa, m);
            pb += __shfl_xor(pb, m);
        }
        if (c == 0) {
            al[node * 12 + rr * 4 + h] = pa;
            ar[node * 12 + rr * 4 + h] = pb;
        }
    }
}

// ---------------------------------------------------------------------------
// K3: degree histogram (by dst) — int atomics
// ---------------------------------------------------------------------------
__global__ __launch_bounds__(256) void hist_kernel(const int* __restrict__ ei,
                                                   int* __restrict__ deg)
{
    const int rr = blockIdx.y;
    const int e  = blockIdx.x * 256 + threadIdx.x;
    if (e < N_EDGES) {
        const int dst = ei[(size_t)rr * 2 * N_EDGES + N_EDGES + e];
        atomicAdd(&deg[rr * N_NODES + dst], 1);
    }
}

// ---------------------------------------------------------------------------
// K4: single-block exclusive scan of deg[3N] -> rowst, cursor
// 1024 threads x 4 elements per iteration
// ---------------------------------------------------------------------------
__global__ __launch_bounds__(1024) void scan_kernel(const int* __restrict__ deg,
    int* __restrict__ rowst, int* __restrict__ cursor, int total)
{
    __shared__ int wsum[16];
    __shared__ int wexcl[16];
    __shared__ int carry_sh;
    const int tid  = threadIdx.x;
    const int lane = tid & 63;
    const int wid  = tid >> 6;
    int carry = 0;
    for (int base = 0; base < total; base += 4096) {
        const int idx = base + tid * 4;
        const int v0 = (idx + 0 < total) ? deg[idx + 0] : 0;
        const int v1 = (idx + 1 < total) ? deg[idx + 1] : 0;
        const int v2 = (idx + 2 < total) ? deg[idx + 2] : 0;
        const int v3 = (idx + 3 < total) ? deg[idx + 3] : 0;
        const int tsum = v0 + v1 + v2 + v3;
        int inc = tsum;
#pragma unroll
        for (int off = 1; off < 64; off <<= 1) {
            const int u = __shfl_up(inc, off);
            if (lane >= off) inc += u;
        }
        if (lane == 63) wsum[wid] = inc;
        __syncthreads();
        if (tid == 0) {
            int s = 0;
#pragma unroll
            for (int i = 0; i < 16; ++i) { const int t2 = wsum[i]; wexcl[i] = s; s += t2; }
            carry_sh = s;
        }
        __syncthreads();
        const int start = carry + wexcl[wid] + (inc - tsum);
        if (idx + 0 < total) { rowst[idx + 0] = start; cursor[idx + 0] = start; }
        const int s1 = start + v0;
        if (idx + 1 < total) { rowst[idx + 1] = s1; cursor[idx + 1] = s1; }
        const int s2 = s1 + v1;
        if (idx + 2 < total) { rowst[idx + 2] = s2; cursor[idx + 2] = s2; }
        const int s3 = s2 + v2;
        if (idx + 3 < total) { rowst[idx + 3] = s3; cursor[idx + 3] = s3; }
        carry += carry_sh;
        __syncthreads();
    }
}

// ---------------------------------------------------------------------------
// K5: scatter src ids into CSR buckets
// ---------------------------------------------------------------------------
__global__ __launch_bounds__(256) void scatter_kernel(const int* __restrict__ ei,
    int* __restrict__ cursor, int* __restrict__ colall)
{
    const int rr = blockIdx.y;
    const int e  = blockIdx.x * 256 + threadIdx.x;
    if (e < N_EDGES) {
        const int src = ei[(size_t)rr * 2 * N_EDGES + e];
        const int dst = ei[(size_t)rr * 2 * N_EDGES + N_EDGES + e];
        const int pos = atomicAdd(&cursor[rr * N_NODES + dst], 1);
        colall[pos] = src;
    }
}

// ---------------------------------------------------------------------------
// K6: fused per-node aggregation (3 relations, edge softmax) + relation-level
//     beta softmax + output.  One 64-lane wave per node; lane L owns channels
//     hc0 = L (head L>>5) and hc1 = L+64 (head (L>>5)+2).
// ---------------------------------------------------------------------------
__global__ __launch_bounds__(256) void aggregate_kernel(
    const float* __restrict__ lbuf, const float* __restrict__ rbuf,
    const float* __restrict__ al,   const float* __restrict__ ar,
    const int* __restrict__ rowst,  const int* __restrict__ deg,
    const int* __restrict__ colall,
    const float* __restrict__ rel_attn_l, const float* __restrict__ rel_attn_r,
    const float* __restrict__ rel_bias,   float* __restrict__ out)
{
    const int n    = (blockIdx.x * blockDim.x + threadIdx.x) >> 6;
    const int lane = threadIdx.x & 63;
    if (n >= N_NODES) return;

    const int h0  = lane >> 5;      // 0 or 1
    const int hc0 = lane;           // h0*32 + c
    const int hc1 = lane + 64;      // (h0+2)*32 + c

    float arr0[3], arr1[3];
#pragma unroll
    for (int rr = 0; rr < 3; ++rr) {
        arr0[rr] = ar[n * 12 + rr * 4 + h0];
        arr1[rr] = ar[n * 12 + rr * 4 + h0 + 2];
    }

    float emb0[3] = {0.f, 0.f, 0.f}, emb1[3] = {0.f, 0.f, 0.f};
    float den0[3] = {0.f, 0.f, 0.f}, den1[3] = {0.f, 0.f, 0.f};

#pragma unroll
    for (int rr = 0; rr < 3; ++rr) {
        const int start = rowst[rr * N_NODES + n];
        const int cnt   = deg[rr * N_NODES + n];
        for (int base = 0; base < cnt; base += 64) {
            const int m = min(64, cnt - base);
            const int srcv = (lane < m) ? colall[start + base + lane] : 0;
            for (int i = 0; i < m; ++i) {
                const int src = __shfl(srcv, i);
                float a0 = al[src * 12 + rr * 4 + h0]     + arr0[rr];
                float a1 = al[src * 12 + rr * 4 + h0 + 2] + arr1[rr];
                a0 = (a0 > 0.f) ? a0 : 0.2f * a0;
                a1 = (a1 > 0.f) ? a1 : 0.2f * a1;
                const float w0 = __expf(a0);
                const float w1 = __expf(a1);
                den0[rr] += w0;
                den1[rr] += w1;
                const float* lr = lbuf + (size_t)src * D_OUTF;
                emb0[rr] = fmaf(w0, lr[hc0], emb0[rr]);
                emb1[rr] = fmaf(w1, lr[hc1], emb1[rr]);
            }
        }
    }

    // normalized relation embeddings + self slot
    float e0[4], e1[4];
#pragma unroll
    for (int rr = 0; rr < 3; ++rr) {
        e0[rr] = emb0[rr] / (den0[rr] + 1e-16f);
        e1[rr] = emb1[rr] / (den1[rr] + 1e-16f);
    }
    const float* lrn = lbuf + (size_t)n * D_OUTF;
    e0[3] = lrn[hc0];
    e1[3] = lrn[hc1];

    // relation-level beta attention
    const float rv0 = rbuf[(size_t)n * D_OUTF + hc0];
    const float rv1 = rbuf[(size_t)n * D_OUTF + hc1];
    const float bl0 = fmaxf(rv0 * rel_attn_l[hc0], 0.f);
    const float bl1 = fmaxf(rv1 * rel_attn_l[hc1], 0.f);

    float beta0[4], beta1[4];
#pragma unroll
    for (int s = 0; s < 4; ++s) {
        const float br0 = fmaxf(e0[s] * rel_attn_r[s * D_OUTF + hc0], 0.f);
        const float br1 = fmaxf(e1[s] * rel_attn_r[s * D_OUTF + hc1], 0.f);
        float p0 = bl0 * br0;
        float p1 = bl1 * br1;
#pragma unroll
        for (int m = 16; m >= 1; m >>= 1) {
            p0 += __shfl_xor(p0, m);
            p1 += __shfl_xor(p1, m);
        }
        beta0[s] = p0 + rel_bias[s];
        beta1[s] = p1 + rel_bias[s];
    }

    // softmax over the 4 relation slots (per head)
    float m0 = fmaxf(fmaxf(beta0[0], beta0[1]), fmaxf(beta0[2], beta0[3]));
    float m1 = fmaxf(fmaxf(beta1[0], beta1[1]), fmaxf(beta1[2], beta1[3]));
    float s0 = 0.f, s1 = 0.f;
#pragma unroll
    for (int s = 0; s < 4; ++s) {
        beta0[s] = __expf(beta0[s] - m0); s0 += beta0[s];
        beta1[s] = __expf(beta1[s] - m1); s1 += beta1[s];
    }
    const float is0 = 1.f / s0, is1 = 1.f / s1;
    float o0 = 0.f, o1 = 0.f;
#pragma unroll
    for (int s = 0; s < 4; ++s) {
        o0 = fmaf(e0[s], beta0[s] * is0, o0);
        o1 = fmaf(e1[s], beta1[s] * is1, o1);
    }
    out[(size_t)n * D_OUTF + hc0] = fmaxf(o0, 0.f);
    out[(size_t)n * D_OUTF + hc1] = fmaxf(o1, 0.f);
}

// ---------------------------------------------------------------------------
extern "C" void kernel_launch(void* const* d_in, const int* in_sizes, int n_in,
                              void* d_out, int out_size, void* d_ws, size_t ws_size,
                              hipStream_t stream)
{
    const float* x     = (const float*)d_in[0];
    const int*   ei    = (const int*)  d_in[1];
    const float* Wl    = (const float*)d_in[2];
    const float* bl    = (const float*)d_in[3];
    const float* Wr    = (const float*)d_in[4];
    const float* br    = (const float*)d_in[5];
    const float* attn  = (const float*)d_in[6];
    const float* ral   = (const float*)d_in[7];
    const float* rar   = (const float*)d_in[8];
    const float* rbias = (const float*)d_in[9];
    float* out = (float*)d_out;

    char* ws = (char*)d_ws;
    size_t off = 0;
    float* lbuf   = (float*)(ws + off); off += (size_t)N_NODES * D_OUTF * 4;   // 51.2 MB
    float* rbuf   = (float*)(ws + off); off += (size_t)N_NODES * D_OUTF * 4;   // 51.2 MB
    float* al     = (float*)(ws + off); off += (size_t)N_NODES * 12 * 4;       // 4.8 MB
    float* ar     = (float*)(ws + off); off += (size_t)N_NODES * 12 * 4;       // 4.8 MB
    int*   deg    = (int*)  (ws + off); off += (size_t)3 * N_NODES * 4;        // 1.2 MB
    int*   rowst  = (int*)  (ws + off); off += (size_t)3 * N_NODES * 4;        // 1.2 MB
    int*   cursor = (int*)  (ws + off); off += (size_t)3 * N_NODES * 4;        // 1.2 MB
    int*   colall = (int*)  (ws + off); off += (size_t)3 * N_EDGES * 4;        // 7.2 MB

    hipMemsetAsync(deg, 0, (size_t)3 * N_NODES * 4, stream);

    proj_kernel<<<N_NODES / 32, 256, 0, stream>>>(x, Wl, bl, Wr, br, lbuf, rbuf);
    alar_kernel<<<N_NODES / 2, 256, 0, stream>>>(lbuf, rbuf, attn, al, ar);

    dim3 eg((N_EDGES + 255) / 256, 3);
    hist_kernel<<<eg, 256, 0, stream>>>(ei, deg);
    scan_kernel<<<1, 1024, 0, stream>>>(deg, rowst, cursor, 3 * N_NODES);
    scatter_kernel<<<eg, 256, 0, stream>>>(ei, cursor, colall);

    aggregate_kernel<<<N_NODES / 4, 256, 0, stream>>>(
        lbuf, rbuf, al, ar, rowst, deg, colall, ral, rar, rbias, out);
}

// Round 2
// 594.322 us; speedup vs baseline: 1.4211x; 1.4211x over previous
//
#include <hip/hip_runtime.h>
#include <hip/hip_bf16.h>

#define N_NODES 100000
#define N_EDGES 600000
#define N_REL   3
#define D_INF   256
#define D_OUTF  128

#define SCAN_TOTAL (3 * N_NODES)                 // 300000
#define SCAN_ELEMS 1024                          // elems per block
#define SCAN_NBLK  ((SCAN_TOTAL + SCAN_ELEMS - 1) / SCAN_ELEMS)  // 293

// ---------------------------------------------------------------------------
// K1: projection GEMM  l = relu(x@Wl+bl), r = relu(x@Wr+br)
// ---------------------------------------------------------------------------
__global__ __launch_bounds__(256) void proj_kernel(
    const float* __restrict__ x,
    const float* __restrict__ Wl, const float* __restrict__ bl,
    const float* __restrict__ Wr, const float* __restrict__ br,
    float* __restrict__ lbuf, float* __restrict__ rbuf)
{
    __shared__ float xs[32 * 256];
    const int tid = threadIdx.x;
    const int nb  = blockIdx.x * 32;

    const float4* xg  = reinterpret_cast<const float4*>(x + (size_t)nb * D_INF);
    float4*       xls = reinterpret_cast<float4*>(xs);
#pragma unroll
    for (int j = 0; j < 8; ++j) xls[tid + j * 256] = xg[tid + j * 256];
    __syncthreads();

    const int cg = tid & 63;   // col group: 4 cols each
    const int ng = tid >> 6;   // node group: 8 nodes each

    const float* wbase;
    const float* bbase;
    float*       obase;
    if (cg < 32) { wbase = Wl + 4 * cg;        bbase = bl + 4 * cg;        obase = lbuf + 4 * cg; }
    else         { wbase = Wr + 4 * (cg - 32); bbase = br + 4 * (cg - 32); obase = rbuf + 4 * (cg - 32); }

    float acc[8][4];
#pragma unroll
    for (int i = 0; i < 8; ++i)
#pragma unroll
        for (int j = 0; j < 4; ++j) acc[i][j] = 0.f;

    const float* xrow = xs + ng * 8 * 256;
#pragma unroll 4
    for (int k = 0; k < 256; ++k) {
        const float4 w = *reinterpret_cast<const float4*>(wbase + k * D_OUTF);
#pragma unroll
        for (int i = 0; i < 8; ++i) {
            const float xv = xrow[i * 256 + k];
            acc[i][0] = fmaf(xv, w.x, acc[i][0]);
            acc[i][1] = fmaf(xv, w.y, acc[i][1]);
            acc[i][2] = fmaf(xv, w.z, acc[i][2]);
            acc[i][3] = fmaf(xv, w.w, acc[i][3]);
        }
    }

    const float4 bias = *reinterpret_cast<const float4*>(bbase);
#pragma unroll
    for (int i = 0; i < 8; ++i) {
        const int node = nb + ng * 8 + i;
        float4 o;
        o.x = fmaxf(acc[i][0] + bias.x, 0.f);
        o.y = fmaxf(acc[i][1] + bias.y, 0.f);
        o.z = fmaxf(acc[i][2] + bias.z, 0.f);
        o.w = fmaxf(acc[i][3] + bias.w, 0.f);
        *reinterpret_cast<float4*>(obase + (size_t)node * D_OUTF) = o;
    }
}

// ---------------------------------------------------------------------------
// K2: per-node attention scalars
// ---------------------------------------------------------------------------
__global__ __launch_bounds__(256) void alar_kernel(
    const float* __restrict__ lbuf, const float* __restrict__ rbuf,
    const float* __restrict__ attn, float* __restrict__ al, float* __restrict__ ar)
{
    const int t    = threadIdx.x;
    const int node = blockIdx.x * 2 + (t >> 7);
    const int hc   = t & 127;
    const int h    = hc >> 5;
    const int c    = hc & 31;
    const float lv = lbuf[(size_t)node * D_OUTF + hc];
    const float rv = rbuf[(size_t)node * D_OUTF + hc];
#pragma unroll
    for (int rr = 0; rr < 3; ++rr) {
        float pa = lv * attn[rr * 256 + h * 64 + c];
        float pb = rv * attn[rr * 256 + h * 64 + 32 + c];
#pragma unroll
        for (int m = 16; m >= 1; m >>= 1) {
            pa += __shfl_xor(pa, m);
            pb += __shfl_xor(pb, m);
        }
        if (c == 0) {
            al[node * 12 + rr * 4 + h] = pa;
            ar[node * 12 + rr * 4 + h] = pb;
        }
    }
}

// ---------------------------------------------------------------------------
// K3: degree histogram (by dst)
// ---------------------------------------------------------------------------
__global__ __launch_bounds__(256) void hist_kernel(const int* __restrict__ ei,
                                                   int* __restrict__ deg)
{
    const int rr = blockIdx.y;
    const int e  = blockIdx.x * 256 + threadIdx.x;
    if (e < N_EDGES) {
        const int dst = ei[(size_t)rr * 2 * N_EDGES + N_EDGES + e];
        atomicAdd(&deg[rr * N_NODES + dst], 1);
    }
}

// ---------------------------------------------------------------------------
// K4a: per-block reduce (1024 elems/block, 256 thr x 4)
// ---------------------------------------------------------------------------
__global__ __launch_bounds__(256) void scan_reduce(const int* __restrict__ deg,
                                                   int* __restrict__ blksum)
{
    __shared__ int ws[4];
    const int tid  = threadIdx.x;
    const int lane = tid & 63;
    const int wid  = tid >> 6;
    const int idx  = blockIdx.x * SCAN_ELEMS + tid * 4;
    int t = 0;
#pragma unroll
    for (int j = 0; j < 4; ++j)
        if (idx + j < SCAN_TOTAL) t += deg[idx + j];
#pragma unroll
    for (int off = 32; off >= 1; off >>= 1) t += __shfl_xor(t, off);
    if (lane == 0) ws[wid] = t;
    __syncthreads();
    if (tid == 0) blksum[blockIdx.x] = ws[0] + ws[1] + ws[2] + ws[3];
}

// ---------------------------------------------------------------------------
// K4b: single-block exclusive scan of the 293 block sums (512 threads)
// ---------------------------------------------------------------------------
__global__ __launch_bounds__(512) void scan_mid(int* __restrict__ blksum)
{
    __shared__ int sh[512];
    const int tid = threadIdx.x;
    const int v = (tid < SCAN_NBLK) ? blksum[tid] : 0;
    sh[tid] = v;
    __syncthreads();
#pragma unroll
    for (int off = 1; off < 512; off <<= 1) {
        const int u = (tid >= off) ? sh[tid - off] : 0;
        __syncthreads();
        sh[tid] += u;
        __syncthreads();
    }
    if (tid < SCAN_NBLK) blksum[tid] = sh[tid] - v;   // exclusive
}

// ---------------------------------------------------------------------------
// K4c: per-block scan + block offset -> rowst, cursor
// ---------------------------------------------------------------------------
__global__ __launch_bounds__(256) void scan_final(const int* __restrict__ deg,
    const int* __restrict__ blkoff, int* __restrict__ rowst,
    int* __restrict__ cursor)
{
    __shared__ int wsum[4];
    __shared__ int wexcl[4];
    const int tid  = threadIdx.x;
    const int lane = tid & 63;
    const int wid  = tid >> 6;
    const int idx  = blockIdx.x * SCAN_ELEMS + tid * 4;

    const int v0 = (idx + 0 < SCAN_TOTAL) ? deg[idx + 0] : 0;
    const int v1 = (idx + 1 < SCAN_TOTAL) ? deg[idx + 1] : 0;
    const int v2 = (idx + 2 < SCAN_TOTAL) ? deg[idx + 2] : 0;
    const int v3 = (idx + 3 < SCAN_TOTAL) ? deg[idx + 3] : 0;
    const int tsum = v0 + v1 + v2 + v3;
    int inc = tsum;
#pragma unroll
    for (int off = 1; off < 64; off <<= 1) {
        const int u = __shfl_up(inc, off);
        if (lane >= off) inc += u;
    }
    if (lane == 63) wsum[wid] = inc;
    __syncthreads();
    if (tid == 0) {
        int s = 0;
#pragma unroll
        for (int i = 0; i < 4; ++i) { const int t2 = wsum[i]; wexcl[i] = s; s += t2; }
    }
    __syncthreads();
    const int start = blkoff[blockIdx.x] + wexcl[wid] + (inc - tsum);
    if (idx + 0 < SCAN_TOTAL) { rowst[idx + 0] = start; cursor[idx + 0] = start; }
    const int s1 = start + v0;
    if (idx + 1 < SCAN_TOTAL) { rowst[idx + 1] = s1; cursor[idx + 1] = s1; }
    const int s2 = s1 + v1;
    if (idx + 2 < SCAN_TOTAL) { rowst[idx + 2] = s2; cursor[idx + 2] = s2; }
    const int s3 = s2 + v2;
    if (idx + 3 < SCAN_TOTAL) { rowst[idx + 3] = s3; cursor[idx + 3] = s3; }
}

// ---------------------------------------------------------------------------
// K5: scatter src ids into CSR buckets
// ---------------------------------------------------------------------------
__global__ __launch_bounds__(256) void scatter_kernel(const int* __restrict__ ei,
    int* __restrict__ cursor, int* __restrict__ colall)
{
    const int rr = blockIdx.y;
    const int e  = blockIdx.x * 256 + threadIdx.x;
    if (e < N_EDGES) {
        const int src = ei[(size_t)rr * 2 * N_EDGES + e];
        const int dst = ei[(size_t)rr * 2 * N_EDGES + N_EDGES + e];
        const int pos = atomicAdd(&cursor[rr * N_NODES + dst], 1);
        colall[pos] = src;
    }
}

// ---------------------------------------------------------------------------
// K6: fused per-node aggregation + relation-level beta softmax + output.
// One 64-lane wave per node; lane L owns channels hc0=L, hc1=L+64.
// Inner edge loop 2x-unrolled for memory-level parallelism.
// ---------------------------------------------------------------------------
__global__ __launch_bounds__(256) void aggregate_kernel(
    const float* __restrict__ lbuf, const float* __restrict__ rbuf,
    const float* __restrict__ al,   const float* __restrict__ ar,
    const int* __restrict__ rowst,  const int* __restrict__ deg,
    const int* __restrict__ colall,
    const float* __restrict__ rel_attn_l, const float* __restrict__ rel_attn_r,
    const float* __restrict__ rel_bias,   float* __restrict__ out)
{
    const int n    = (blockIdx.x * blockDim.x + threadIdx.x) >> 6;
    const int lane = threadIdx.x & 63;
    if (n >= N_NODES) return;

    const int h0  = lane >> 5;      // 0 or 1
    const int hc0 = lane;           // h0*32 + c
    const int hc1 = lane + 64;      // (h0+2)*32 + c

    float arr0[3], arr1[3];
#pragma unroll
    for (int rr = 0; rr < 3; ++rr) {
        arr0[rr] = ar[n * 12 + rr * 4 + h0];
        arr1[rr] = ar[n * 12 + rr * 4 + h0 + 2];
    }

    float emb0[3] = {0.f, 0.f, 0.f}, emb1[3] = {0.f, 0.f, 0.f};
    float den0[3] = {0.f, 0.f, 0.f}, den1[3] = {0.f, 0.f, 0.f};

#pragma unroll
    for (int rr = 0; rr < 3; ++rr) {
        const int start = rowst[rr * N_NODES + n];
        const int cnt   = deg[rr * N_NODES + n];
        for (int base = 0; base < cnt; base += 64) {
            const int m = min(64, cnt - base);
            const int srcv = (lane < m) ? colall[start + base + lane] : 0;
            int i = 0;
            for (; i + 1 < m; i += 2) {
                const int sA = __shfl(srcv, i);
                const int sB = __shfl(srcv, i + 1);
                // issue all 6 loads up front (2 al entries + 4 row elements)
                const float alA0 = al[sA * 12 + rr * 4 + h0];
                const float alA1 = al[sA * 12 + rr * 4 + h0 + 2];
                const float alB0 = al[sB * 12 + rr * 4 + h0];
                const float alB1 = al[sB * 12 + rr * 4 + h0 + 2];
                const float* lrA = lbuf + (size_t)sA * D_OUTF;
                const float* lrB = lbuf + (size_t)sB * D_OUTF;
                const float lA0 = lrA[hc0], lA1 = lrA[hc1];
                const float lB0 = lrB[hc0], lB1 = lrB[hc1];
                float aA0 = alA0 + arr0[rr];
                float aA1 = alA1 + arr1[rr];
                float aB0 = alB0 + arr0[rr];
                float aB1 = alB1 + arr1[rr];
                aA0 = (aA0 > 0.f) ? aA0 : 0.2f * aA0;
                aA1 = (aA1 > 0.f) ? aA1 : 0.2f * aA1;
                aB0 = (aB0 > 0.f) ? aB0 : 0.2f * aB0;
                aB1 = (aB1 > 0.f) ? aB1 : 0.2f * aB1;
                const float wA0 = __expf(aA0), wA1 = __expf(aA1);
                const float wB0 = __expf(aB0), wB1 = __expf(aB1);
                den0[rr] += wA0 + wB0;
                den1[rr] += wA1 + wB1;
                emb0[rr] = fmaf(wA0, lA0, emb0[rr]);
                emb1[rr] = fmaf(wA1, lA1, emb1[rr]);
                emb0[rr] = fmaf(wB0, lB0, emb0[rr]);
                emb1[rr] = fmaf(wB1, lB1, emb1[rr]);
            }
            if (i < m) {
                const int src = __shfl(srcv, i);
                float a0 = al[src * 12 + rr * 4 + h0]     + arr0[rr];
                float a1 = al[src * 12 + rr * 4 + h0 + 2] + arr1[rr];
                a0 = (a0 > 0.f) ? a0 : 0.2f * a0;
                a1 = (a1 > 0.f) ? a1 : 0.2f * a1;
                const float w0 = __expf(a0);
                const float w1 = __expf(a1);
                den0[rr] += w0;
                den1[rr] += w1;
                const float* lr = lbuf + (size_t)src * D_OUTF;
                emb0[rr] = fmaf(w0, lr[hc0], emb0[rr]);
                emb1[rr] = fmaf(w1, lr[hc1], emb1[rr]);
            }
        }
    }

    // normalized relation embeddings + self slot
    float e0[4], e1[4];
#pragma unroll
    for (int rr = 0; rr < 3; ++rr) {
        e0[rr] = emb0[rr] / (den0[rr] + 1e-16f);
        e1[rr] = emb1[rr] / (den1[rr] + 1e-16f);
    }
    const float* lrn = lbuf + (size_t)n * D_OUTF;
    e0[3] = lrn[hc0];
    e1[3] = lrn[hc1];

    // relation-level beta attention
    const float rv0 = rbuf[(size_t)n * D_OUTF + hc0];
    const float rv1 = rbuf[(size_t)n * D_OUTF + hc1];
    const float bl0 = fmaxf(rv0 * rel_attn_l[hc0], 0.f);
    const float bl1 = fmaxf(rv1 * rel_attn_l[hc1], 0.f);

    float beta0[4], beta1[4];
#pragma unroll
    for (int s = 0; s < 4; ++s) {
        const float br0 = fmaxf(e0[s] * rel_attn_r[s * D_OUTF + hc0], 0.f);
        const float br1 = fmaxf(e1[s] * rel_attn_r[s * D_OUTF + hc1], 0.f);
        float p0 = bl0 * br0;
        float p1 = bl1 * br1;
#pragma unroll
        for (int m = 16; m >= 1; m >>= 1) {
            p0 += __shfl_xor(p0, m);
            p1 += __shfl_xor(p1, m);
        }
        beta0[s] = p0 + rel_bias[s];
        beta1[s] = p1 + rel_bias[s];
    }

    // softmax over the 4 relation slots (per head)
    float m0 = fmaxf(fmaxf(beta0[0], beta0[1]), fmaxf(beta0[2], beta0[3]));
    float m1 = fmaxf(fmaxf(beta1[0], beta1[1]), fmaxf(beta1[2], beta1[3]));
    float s0 = 0.f, s1 = 0.f;
#pragma unroll
    for (int s = 0; s < 4; ++s) {
        beta0[s] = __expf(beta0[s] - m0); s0 += beta0[s];
        beta1[s] = __expf(beta1[s] - m1); s1 += beta1[s];
    }
    const float is0 = 1.f / s0, is1 = 1.f / s1;
    float o0 = 0.f, o1 = 0.f;
#pragma unroll
    for (int s = 0; s < 4; ++s) {
        o0 = fmaf(e0[s], beta0[s] * is0, o0);
        o1 = fmaf(e1[s], beta1[s] * is1, o1);
    }
    out[(size_t)n * D_OUTF + hc0] = fmaxf(o0, 0.f);
    out[(size_t)n * D_OUTF + hc1] = fmaxf(o1, 0.f);
}

// ---------------------------------------------------------------------------
extern "C" void kernel_launch(void* const* d_in, const int* in_sizes, int n_in,
                              void* d_out, int out_size, void* d_ws, size_t ws_size,
                              hipStream_t stream)
{
    const float* x     = (const float*)d_in[0];
    const int*   ei    = (const int*)  d_in[1];
    const float* Wl    = (const float*)d_in[2];
    const float* bl    = (const float*)d_in[3];
    const float* Wr    = (const float*)d_in[4];
    const float* br    = (const float*)d_in[5];
    const float* attn  = (const float*)d_in[6];
    const float* ral   = (const float*)d_in[7];
    const float* rar   = (const float*)d_in[8];
    const float* rbias = (const float*)d_in[9];
    float* out = (float*)d_out;

    char* ws = (char*)d_ws;
    size_t off = 0;
    float* lbuf   = (float*)(ws + off); off += (size_t)N_NODES * D_OUTF * 4;   // 51.2 MB
    float* rbuf   = (float*)(ws + off); off += (size_t)N_NODES * D_OUTF * 4;   // 51.2 MB
    float* al     = (float*)(ws + off); off += (size_t)N_NODES * 12 * 4;       // 4.8 MB
    float* ar     = (float*)(ws + off); off += (size_t)N_NODES * 12 * 4;       // 4.8 MB
    int*   deg    = (int*)  (ws + off); off += (size_t)3 * N_NODES * 4;        // 1.2 MB
    int*   rowst  = (int*)  (ws + off); off += (size_t)3 * N_NODES * 4;        // 1.2 MB
    int*   cursor = (int*)  (ws + off); off += (size_t)3 * N_NODES * 4;        // 1.2 MB
    int*   colall = (int*)  (ws + off); off += (size_t)3 * N_EDGES * 4;        // 7.2 MB
    int*   blksum = (int*)  (ws + off); off += (size_t)512 * 4;

    hipMemsetAsync(deg, 0, (size_t)3 * N_NODES * 4, stream);

    proj_kernel<<<N_NODES / 32, 256, 0, stream>>>(x, Wl, bl, Wr, br, lbuf, rbuf);
    alar_kernel<<<N_NODES / 2, 256, 0, stream>>>(lbuf, rbuf, attn, al, ar);

    dim3 eg((N_EDGES + 255) / 256, 3);
    hist_kernel<<<eg, 256, 0, stream>>>(ei, deg);
    scan_reduce<<<SCAN_NBLK, 256, 0, stream>>>(deg, blksum);
    scan_mid<<<1, 512, 0, stream>>>(blksum);
    scan_final<<<SCAN_NBLK, 256, 0, stream>>>(deg, blksum, rowst, cursor);
    scatter_kernel<<<eg, 256, 0, stream>>>(ei, cursor, colall);

    aggregate_kernel<<<N_NODES / 4, 256, 0, stream>>>(
        lbuf, rbuf, al, ar, rowst, deg, colall, ral, rar, rbias, out);
}